// Round 15
// baseline (554.151 us; speedup 1.0000x reference)
//
#include <hip/hip_runtime.h>

static constexpr int B_ = 8;
static constexpr int N_ = 16384;
static constexpr int D_ = 256;
static constexpr int L_ = 64;

static constexpr int TPB = 512;       // 256 WGs x 512 thr, 1 WG/CU (LDS-forced), 1 point/thread
static constexpr int LF4 = 18;        // dims 0..71 in LDS
static constexpr int RF4 = 64 - LF4;  // dims 72..255 in VGPRs (46 float4)

// ws layout (init zeroes 69664 B every call; ws poisoned 0xAA once):
//   rec  [8][2][32] records, each 128 B    @ 0     (65536 B)
//        record u64[0]=key (tagged), u64[1]=enc (tagged); one WG per line.
//   gadj u32[8][128]                       @ 65536 ( 4096 B)
//   cnt  u32[8]                            @ 69632 (   32 B)

__global__ void __launch_bounds__(1024)
init_kernel(unsigned int* __restrict__ z)
{
    z[blockIdx.x * 1024 + threadIdx.x] = 0u;   // grid 18 -> 73728 B
}

// ---------------------------------------------------------------------------
// Fused FPS scan + witness + finalize. Single-phase barrier, hot poll,
// PRIVATE-LINE publish: each WG's per-step record occupies its own 128-B
// cache line (no same-line store serialization at the LLC — the r5..r14
// packed layout had 8 publishers/line). 2-slot rotating window with step
// tags: key = dist<<32 | s<<14 | (16383-n), enc = s<<32 | norm_bits; pollers
// require BOTH tags == s, rejecting stale window reuse, cross-replay
// leftovers, and 0xAA poison. Window reuse is race-free: publishing s+2
// requires all WGs past barrier s+1, hence past poll s.
// All FMA/compare orders bit-identical to the r5..r14-validated kernels.
// ---------------------------------------------------------------------------
__global__ __attribute__((amdgpu_flat_work_group_size(512, 512),
                          amdgpu_waves_per_eu(2, 2)))
void fps_all_kernel(const float* __restrict__ emb, const float* __restrict__ csp,
                    unsigned long long* __restrict__ rec,
                    unsigned int* __restrict__ gadj,
                    unsigned int* __restrict__ cnt,
                    float* __restrict__ out)
{
    const int wg  = blockIdx.x;        // 0..255
    const int b   = wg & 7;            // batch == presumed XCD (round-robin)
    const int wib = wg >> 3;           // 0..31 within batch
    const int tid = threadIdx.x;
    const int n   = (wib << 9) + tid;  // my point
    const float c = fabsf(csp[0]);

    __shared__ float4 slab[LF4 * TPB];          // 147456 B resident slice
    __shared__ float wval[8];
    __shared__ int   widx[8];
    __shared__ float wxn[8];
    __shared__ int   s_next;
    __shared__ float s_lmn;
    __shared__ int   s_lead;
    __shared__ unsigned int lmask[128];
    __shared__ int   labels[64];

    if (tid < 128) lmask[tid] = 0u;

    const float4* __restrict__ pt = (const float4*)(emb + (size_t)(b * N_ + n) * D_);

    // resident load + norm (sequential 4-acc over k=0..63, matches r1..r14)
    float4 p[RF4];
    float s0 = 0.f, s1 = 0.f, s2 = 0.f, s3 = 0.f;
    #pragma unroll
    for (int k = 0; k < LF4; ++k) {
        float4 v = pt[k];
        slab[k * TPB + tid] = v;
        s0 = fmaf(v.x, v.x, s0); s1 = fmaf(v.y, v.y, s1);
        s2 = fmaf(v.z, v.z, s2); s3 = fmaf(v.w, v.w, s3);
    }
    #pragma unroll
    for (int k = 0; k < RF4; ++k) {
        float4 v = pt[LF4 + k];
        p[k] = v;
        s0 = fmaf(v.x, v.x, s0); s1 = fmaf(v.y, v.y, s1);
        s2 = fmaf(v.z, v.z, s2); s3 = fmaf(v.w, v.w, s3);
    }
    const float my_xn = (s0 + s1) + (s2 + s3);

    float min_d = __builtin_inff();
    float b1v = __builtin_inff(), b2v = __builtin_inff();
    int   b1i = 0, b2i = 0;
    int   lm    = 0;      // landmark 0 = point 0
    float lmn_c = 0.f;

    #pragma unroll 1
    for (int s = 1; s <= L_; ++s) {
        // uniform (SGPR) pointer to landmark row s-1 — scalar-load path (r10)
        const int lmU = __builtin_amdgcn_readfirstlane(lm);
        const float4* __restrict__ w4 =
            (const float4*)(emb + (size_t)(b * N_ + lmU) * D_);

        float lmn;
        if (s == 1) {
            // landmark 0's norm computed locally (same 4-acc k-ascending order)
            float t0 = 0.f, t1 = 0.f, t2 = 0.f, t3 = 0.f;
            #pragma unroll
            for (int k = 0; k < 64; ++k) {
                float4 w = w4[k];
                t0 = fmaf(w.x, w.x, t0); t1 = fmaf(w.y, w.y, t1);
                t2 = fmaf(w.z, w.z, t2); t3 = fmaf(w.w, w.w, t3);
            }
            lmn = (t0 + t1) + (t2 + t3);
        } else {
            lmn = lmn_c;   // winner's xn carried through the barrier (r5..r14)
        }

        float d0 = 0.f, d1 = 0.f, d2 = 0.f, d3 = 0.f;
        #pragma unroll
        for (int k = 0; k < LF4; ++k) {
            float4 v = slab[k * TPB + tid];
            float4 w = w4[k];
            d0 = fmaf(v.x, w.x, d0); d1 = fmaf(v.y, w.y, d1);
            d2 = fmaf(v.z, w.z, d2); d3 = fmaf(v.w, w.w, d3);
        }
        #pragma unroll
        for (int k = 0; k < RF4; ++k) {
            float4 v = p[k];
            float4 w = w4[LF4 + k];
            d0 = fmaf(v.x, w.x, d0); d1 = fmaf(v.y, w.y, d1);
            d2 = fmaf(v.z, w.z, d2); d3 = fmaf(v.w, w.w, d3);
        }
        const float dot  = (d0 + d1) + (d2 + d3);
        const float diff = fmaxf(my_xn + lmn - 2.f * dot, 1e-10f);
        const float fac  = fmaxf(1.f + c * my_xn + c * lmn, 1e-6f);
        const float d    = sqrtf(diff) * sqrtf(fac);

        // fused witness: landmark POSITION s-1, ascending order, strict '<'
        if (d < b1v)      { b2v = b1v; b2i = b1i; b1v = d; b1i = s - 1; }
        else if (d < b2v) { b2v = d; b2i = s - 1; }

        if (s == L_) break;

        min_d = fminf(min_d, d);

        // wave argmax (tie -> lower n), carrying candidate's xn
        float v = min_d; int i = n; float x = my_xn;
        #pragma unroll
        for (int off = 32; off >= 1; off >>= 1) {
            float ov = __shfl_down(v, off);
            int   oi = __shfl_down(i, off);
            float ox = __shfl_down(x, off);
            if (ov > v || (ov == v && oi < i)) { v = ov; i = oi; x = ox; }
        }
        if ((tid & 63) == 0) {
            const int w = tid >> 6;
            wval[w] = v; widx[w] = i; wxn[w] = x;
        }
        __syncthreads();

        if (tid < 64) {   // wave 0: publish (private line), hot-poll, reduce
            v = (tid < 8) ? wval[tid] : -__builtin_inff();
            i = (tid < 8) ? widx[tid] : 0x7FFFFFFF;
            x = (tid < 8) ? wxn[tid]  : 0.f;
            #pragma unroll
            for (int off = 4; off >= 1; off >>= 1) {
                float ov = __shfl_down(v, off);
                int   oi = __shfl_down(i, off);
                float ox = __shfl_down(x, off);
                if (ov > v || (ov == v && oi < i)) { v = ov; i = oi; x = ox; }
            }
            // u64 index of record base: ((b*2 + (s&1))*32 + lane) * 16
            const size_t sbase = (size_t)(b * 2 + (s & 1)) * 32 * 16;
            if (tid == 0) {
                const unsigned long long key =
                    ((unsigned long long)__float_as_uint(v) << 32) |
                    ((unsigned)(s & 0xFF) << 14) |
                    (unsigned)(16383 - i);                    // tag + tie-break
                const unsigned long long enc64 =
                    ((unsigned long long)(unsigned)s << 32) |
                    (unsigned long long)(unsigned)__float_as_uint(x);  // tag + norm
                // UNORDERED publish to my private 128-B line.
                __hip_atomic_store(&rec[sbase + (size_t)wib * 16 + 0], key,
                                   __ATOMIC_RELAXED, __HIP_MEMORY_SCOPE_AGENT);
                __hip_atomic_store(&rec[sbase + (size_t)wib * 16 + 1], enc64,
                                   __ATOMIC_RELAXED, __HIP_MEMORY_SCOPE_AGENT);
            }
            // hot poll: lane l -> record l (32 distinct lines, parallel);
            // exit only when BOTH tags match s (stale/poison rejected).
            unsigned long long myk, mye;
            for (;;) {
                myk = __hip_atomic_load(&rec[sbase + (size_t)(tid & 31) * 16 + 0],
                                        __ATOMIC_RELAXED, __HIP_MEMORY_SCOPE_AGENT);
                mye = __hip_atomic_load(&rec[sbase + (size_t)(tid & 31) * 16 + 1],
                                        __ATOMIC_RELAXED, __HIP_MEMORY_SCOPE_AGENT);
                const bool ok = (((myk >> 14) & 0xFFull) == (unsigned long long)(s & 0xFF)) &&
                                ((mye >> 32) == (unsigned long long)(unsigned)s);
                if (__all(ok)) break;
            }
            // max-reduce 32 distinct keys, carrying enc (lanes 32..63 duplicate)
            unsigned long long k = myk, e = mye;
            #pragma unroll
            for (int off = 32; off >= 1; off >>= 1) {
                unsigned long long ok2 = __shfl_down(k, off);
                unsigned long long oe  = __shfl_down(e, off);
                if (ok2 > k) { k = ok2; e = oe; }
            }
            if (tid == 0) {
                s_next = (int)(16383u - (unsigned)(k & 0x3FFFull));
                s_lmn  = __uint_as_float((unsigned)(e & 0xFFFFFFFFull));
            }
        }
        __syncthreads();
        lm    = s_next;
        lmn_c = s_lmn;
    }

    // emit my edge (top-2 landmark positions) into LDS bitmask
    {
        const int lo = min(b1i, b2i), hi = max(b1i, b2i);
        const int bitpos = lo * 64 + hi;
        atomicOr(&lmask[bitpos >> 5], 1u << (bitpos & 31));
    }
    __syncthreads();
    if (tid < 128) {
        unsigned w = lmask[tid];
        if (w) atomicOr(&gadj[b * 128 + tid], w);   // agent-scope RMW at LLC
    }
    __syncthreads();

    if (tid == 0) {
        __threadfence();
        unsigned prev = atomicAdd(&cnt[b], 1u);
        s_lead = (prev == 31u) ? 1 : 0;
    }
    __syncthreads();
    if (!s_lead) return;

    // ---- leader WG (last arriver): finalize this batch ----
    __threadfence();
    if (tid < 128) lmask[tid] = atomicOr(&gadj[b * 128 + tid], 0u);  // coherent read
    __syncthreads();

    unsigned long long m = 0ull;
    if (tid < 64) {
        m = ((unsigned long long)lmask[tid * 2 + 1] << 32) | lmask[tid * 2];
        for (int j = 0; j < 64; ++j)           // symmetrize: column bits
            if (lmask[j * 2 + (tid >> 5)] & (1u << (tid & 31))) m |= 1ull << j;
        labels[tid] = tid;
    }
    __syncthreads();

    for (int it = 0; it < 64; ++it) {          // synchronous min-label propagation
        int mn = 0;
        if (tid < 64) {
            mn = labels[tid];
            unsigned long long mm = m;
            while (mm) {
                int j = __ffsll(mm) - 1;
                int lj = labels[j];
                mn = mn < lj ? mn : lj;
                mm &= mm - 1;
            }
        }
        __syncthreads();
        if (tid < 64) labels[tid] = mn;
        __syncthreads();
    }

    if (tid < 64) {
        unsigned long long hi_mask = (tid < 63) ? (~0ull << (tid + 1)) : 0ull;
        int myedges = __popcll(m & hi_mask);
        int mycomp  = (labels[tid] == tid) ? 1 : 0;
        #pragma unroll
        for (int off = 32; off >= 1; off >>= 1) {
            myedges += __shfl_down(myedges, off);
            mycomp  += __shfl_down(mycomp, off);
        }
        if (tid == 0) {
            float beta0 = (float)mycomp;
            float beta1 = (float)(myedges - (64 - mycomp));
            out[b]      = beta0;
            out[8 + b]  = beta1;
            out[16 + b] = beta0 / 64.f;
            out[24 + b] = (beta1 > 3.f) ? 1.f : 0.f;
        }
    }
}

// ---------------------------------------------------------------------------
extern "C" void kernel_launch(void* const* d_in, const int* in_sizes, int n_in,
                              void* d_out, int out_size, void* d_ws, size_t ws_size,
                              hipStream_t stream)
{
    const float* emb = (const float*)d_in[0];
    const float* cs  = (const float*)d_in[1];
    float* out = (float*)d_out;

    char* ws = (char*)d_ws;
    unsigned long long* rec  = (unsigned long long*)(ws);
    unsigned int*       gadj = (unsigned int*)(ws + 65536);
    unsigned int*       cnt  = (unsigned int*)(ws + 69632);

    hipLaunchKernelGGL(init_kernel, dim3(18), dim3(1024), 0, stream,
                       (unsigned int*)ws);
    hipLaunchKernelGGL(fps_all_kernel, dim3(256), dim3(TPB), 0, stream,
                       emb, cs, rec, gadj, cnt, out);
}

// Round 17
// 551.019 us; speedup vs baseline: 1.0057x; 1.0057x over previous
//
#include <hip/hip_runtime.h>

static constexpr int B_ = 8;
static constexpr int N_ = 16384;
static constexpr int D_ = 256;
static constexpr int L_ = 64;

static constexpr int TPB = 512;       // 256 WGs x 512 thr, 1 WG/CU (LDS-forced), 1 point/thread
static constexpr int LF4 = 18;        // dims 0..71 in LDS
static constexpr int RF4 = 64 - LF4;  // dims 72..255 in VGPRs/AGPRs (46 float4)

// ws layout (init zeroes 81920 B every call; ws poisoned 0xAA once):
//   rec   u64[8][2][32][2]          @ 0      ( 8192 B)  packed {key,enc} per WG per slot
//   bcast [8][2][32] x 128 B        @ 8192   (65536 B)  winner copy per READER (private line)
//   gadj  u32[8][128]               @ 73728  ( 4096 B)
//   cnt   u32[8]                    @ 77824  (   32 B)
// All sync words tag-validated (key bits[21:14]=s&0xFF, enc hi32=s), so
// zero-init / 0xAA poison / stale window reuse all fail the check and retry.

__global__ void __launch_bounds__(1024)
init_kernel(unsigned int* __restrict__ z)
{
    z[blockIdx.x * 1024 + threadIdx.x] = 0u;   // grid 20 -> 81920 B
}

// ---------------------------------------------------------------------------
// Fused FPS scan + witness + finalize. Hierarchical low-contention barrier:
//   publish: every WG stores {key,enc} (2 relaxed agent stores, unordered).
//   master (wib 0): polls all 32 records with ONE load per lane (64 lanes =
//     32 keys + 32 encs), tag-validated; reduces; broadcasts winner to 32
//     PRIVATE 128-B lines (one per reader WG).
//   readers: ONE lane polls own private line (2 loads/iter, tag-validated).
// Poll concurrency ~100 requests vs ~32K in the r13..r15 flat scheme —
// attacks LLC queuing, the suspected residual of the ~8us/step rendezvous.
// No sc0 anywhere (r7/r16 proved it deadlock-prone). Deadlock-free: records
// are always published before any poll; bcast always follows master detect.
// All FMA/compare orders bit-identical to the r5..r15-validated kernels.
// ---------------------------------------------------------------------------
__global__ __attribute__((amdgpu_flat_work_group_size(512, 512),
                          amdgpu_waves_per_eu(2, 2)))
void fps_all_kernel(const float* __restrict__ emb, const float* __restrict__ csp,
                    unsigned long long* __restrict__ rec,
                    unsigned long long* __restrict__ bcast,
                    unsigned int* __restrict__ gadj,
                    unsigned int* __restrict__ cnt,
                    float* __restrict__ out)
{
    const int wg  = blockIdx.x;        // 0..255
    const int b   = wg & 7;            // batch (XCD-aligned under round-robin)
    const int wib = wg >> 3;           // 0..31 within batch
    const int tid = threadIdx.x;
    const int n   = (wib << 9) + tid;  // my point
    const float c = fabsf(csp[0]);

    __shared__ float4 slab[LF4 * TPB];          // 147456 B resident slice
    __shared__ float wval[8];
    __shared__ int   widx[8];
    __shared__ float wxn[8];
    __shared__ int   s_next;
    __shared__ float s_lmn;
    __shared__ int   s_lead;
    __shared__ unsigned int lmask[128];
    __shared__ int   labels[64];

    if (tid < 128) lmask[tid] = 0u;

    const float4* __restrict__ pt = (const float4*)(emb + (size_t)(b * N_ + n) * D_);

    // resident load + norm (sequential 4-acc over k=0..63, matches r1..r15)
    float4 p[RF4];
    float s0 = 0.f, s1 = 0.f, s2 = 0.f, s3 = 0.f;
    #pragma unroll
    for (int k = 0; k < LF4; ++k) {
        float4 v = pt[k];
        slab[k * TPB + tid] = v;
        s0 = fmaf(v.x, v.x, s0); s1 = fmaf(v.y, v.y, s1);
        s2 = fmaf(v.z, v.z, s2); s3 = fmaf(v.w, v.w, s3);
    }
    #pragma unroll
    for (int k = 0; k < RF4; ++k) {
        float4 v = pt[LF4 + k];
        p[k] = v;
        s0 = fmaf(v.x, v.x, s0); s1 = fmaf(v.y, v.y, s1);
        s2 = fmaf(v.z, v.z, s2); s3 = fmaf(v.w, v.w, s3);
    }
    const float my_xn = (s0 + s1) + (s2 + s3);

    float min_d = __builtin_inff();
    float b1v = __builtin_inff(), b2v = __builtin_inff();
    int   b1i = 0, b2i = 0;
    int   lm    = 0;      // landmark 0 = point 0
    float lmn_c = 0.f;

    #pragma unroll 1
    for (int s = 1; s <= L_; ++s) {
        // uniform (SGPR) pointer to landmark row s-1 — scalar-load path (r10)
        const int lmU = __builtin_amdgcn_readfirstlane(lm);
        const float4* __restrict__ w4 =
            (const float4*)(emb + (size_t)(b * N_ + lmU) * D_);

        float lmn;
        if (s == 1) {
            // landmark 0's norm computed locally (same 4-acc k-ascending order)
            float t0 = 0.f, t1 = 0.f, t2 = 0.f, t3 = 0.f;
            #pragma unroll
            for (int k = 0; k < 64; ++k) {
                float4 w = w4[k];
                t0 = fmaf(w.x, w.x, t0); t1 = fmaf(w.y, w.y, t1);
                t2 = fmaf(w.z, w.z, t2); t3 = fmaf(w.w, w.w, t3);
            }
            lmn = (t0 + t1) + (t2 + t3);
        } else {
            lmn = lmn_c;   // winner's xn carried through the barrier (r5..r15)
        }

        float d0 = 0.f, d1 = 0.f, d2 = 0.f, d3 = 0.f;
        #pragma unroll
        for (int k = 0; k < LF4; ++k) {
            float4 v = slab[k * TPB + tid];
            float4 w = w4[k];
            d0 = fmaf(v.x, w.x, d0); d1 = fmaf(v.y, w.y, d1);
            d2 = fmaf(v.z, w.z, d2); d3 = fmaf(v.w, w.w, d3);
        }
        #pragma unroll
        for (int k = 0; k < RF4; ++k) {
            float4 v = p[k];
            float4 w = w4[LF4 + k];
            d0 = fmaf(v.x, w.x, d0); d1 = fmaf(v.y, w.y, d1);
            d2 = fmaf(v.z, w.z, d2); d3 = fmaf(v.w, w.w, d3);
        }
        const float dot  = (d0 + d1) + (d2 + d3);
        const float diff = fmaxf(my_xn + lmn - 2.f * dot, 1e-10f);
        const float fac  = fmaxf(1.f + c * my_xn + c * lmn, 1e-6f);
        const float d    = sqrtf(diff) * sqrtf(fac);

        // fused witness: landmark POSITION s-1, ascending order, strict '<'
        if (d < b1v)      { b2v = b1v; b2i = b1i; b1v = d; b1i = s - 1; }
        else if (d < b2v) { b2v = d; b2i = s - 1; }

        if (s == L_) break;

        min_d = fminf(min_d, d);

        // wave argmax (tie -> lower n), carrying candidate's xn
        float v = min_d; int i = n; float x = my_xn;
        #pragma unroll
        for (int off = 32; off >= 1; off >>= 1) {
            float ov = __shfl_down(v, off);
            int   oi = __shfl_down(i, off);
            float ox = __shfl_down(x, off);
            if (ov > v || (ov == v && oi < i)) { v = ov; i = oi; x = ox; }
        }
        if ((tid & 63) == 0) {
            const int w = tid >> 6;
            wval[w] = v; widx[w] = i; wxn[w] = x;
        }
        __syncthreads();

        const int par = s & 1;
        const size_t recbase = (size_t)(b * 2 + par) * 64;        // u64 idx
        const size_t bbase   = (size_t)(b * 2 + par) * 32 * 16;   // u64 idx
        const unsigned long long tagk = (unsigned long long)(s & 0xFF);
        const unsigned long long tage = (unsigned long long)(unsigned)s;

        if (tid < 64) {
            // block reduce (8 wave leaders), then publish my WG's record
            v = (tid < 8) ? wval[tid] : -__builtin_inff();
            i = (tid < 8) ? widx[tid] : 0x7FFFFFFF;
            x = (tid < 8) ? wxn[tid]  : 0.f;
            #pragma unroll
            for (int off = 4; off >= 1; off >>= 1) {
                float ov = __shfl_down(v, off);
                int   oi = __shfl_down(i, off);
                float ox = __shfl_down(x, off);
                if (ov > v || (ov == v && oi < i)) { v = ov; i = oi; x = ox; }
            }
            if (tid == 0) {
                const unsigned long long key =
                    ((unsigned long long)__float_as_uint(v) << 32) |
                    ((unsigned)(s & 0xFF) << 14) |
                    (unsigned)(16383 - i);                    // tag + tie-break
                const unsigned long long enc64 =
                    ((unsigned long long)(unsigned)s << 32) |
                    (unsigned long long)(unsigned)__float_as_uint(x);
                __hip_atomic_store(&rec[recbase + (size_t)wib * 2 + 0], key,
                                   __ATOMIC_RELAXED, __HIP_MEMORY_SCOPE_AGENT);
                __hip_atomic_store(&rec[recbase + (size_t)wib * 2 + 1], enc64,
                                   __ATOMIC_RELAXED, __HIP_MEMORY_SCOPE_AGENT);
            }

            if (wib == 0) {
                // MASTER: one load per lane covers 32 keys (even lanes) +
                // 32 encs (odd lanes); tag-validate both kinds.
                unsigned long long myw;
                for (;;) {
                    myw = __hip_atomic_load(&rec[recbase + tid],
                                            __ATOMIC_RELAXED, __HIP_MEMORY_SCOPE_AGENT);
                    const bool ok = ((tid & 1) == 0)
                        ? (((myw >> 14) & 0xFFull) == tagk)
                        : ((myw >> 32) == tage);
                    if (__all(ok)) break;
                }
                // pair up: even lane 2k holds key k; pull enc k from lane 2k+1
                unsigned long long e = __shfl_down(myw, 1);
                unsigned long long k = ((tid & 1) == 0) ? myw : 0ull;
                #pragma unroll
                for (int off = 32; off >= 2; off >>= 1) {
                    unsigned long long ok2 = __shfl_down(k, off);
                    unsigned long long oe  = __shfl_down(e, off);
                    if (ok2 > k) { k = ok2; e = oe; }
                }
                // broadcast winner to 32 private reader lines
                const unsigned long long wk = __shfl(k, 0);
                const unsigned long long we = __shfl(e, 0);
                if (tid < 32) {
                    __hip_atomic_store(&bcast[bbase + (size_t)tid * 16 + 0], wk,
                                       __ATOMIC_RELAXED, __HIP_MEMORY_SCOPE_AGENT);
                    __hip_atomic_store(&bcast[bbase + (size_t)tid * 16 + 1], we,
                                       __ATOMIC_RELAXED, __HIP_MEMORY_SCOPE_AGENT);
                }
                if (tid == 0) {
                    s_next = (int)(16383u - (unsigned)(wk & 0x3FFFull));
                    s_lmn  = __uint_as_float((unsigned)(we & 0xFFFFFFFFull));
                }
            } else if (tid == 0) {
                // READER: single lane polls own private line
                unsigned long long bk, be;
                for (;;) {
                    bk = __hip_atomic_load(&bcast[bbase + (size_t)wib * 16 + 0],
                                           __ATOMIC_RELAXED, __HIP_MEMORY_SCOPE_AGENT);
                    be = __hip_atomic_load(&bcast[bbase + (size_t)wib * 16 + 1],
                                           __ATOMIC_RELAXED, __HIP_MEMORY_SCOPE_AGENT);
                    if ((((bk >> 14) & 0xFFull) == tagk) && ((be >> 32) == tage))
                        break;
                }
                s_next = (int)(16383u - (unsigned)(bk & 0x3FFFull));
                s_lmn  = __uint_as_float((unsigned)(be & 0xFFFFFFFFull));
            }
        }
        __syncthreads();
        lm    = s_next;
        lmn_c = s_lmn;
    }

    // emit my edge (top-2 landmark positions) into LDS bitmask
    {
        const int lo = min(b1i, b2i), hi = max(b1i, b2i);
        const int bitpos = lo * 64 + hi;
        atomicOr(&lmask[bitpos >> 5], 1u << (bitpos & 31));
    }
    __syncthreads();
    if (tid < 128) {
        unsigned w = lmask[tid];
        if (w) atomicOr(&gadj[b * 128 + tid], w);   // agent-scope RMW at LLC
    }
    __syncthreads();

    if (tid == 0) {
        __threadfence();
        unsigned prev = atomicAdd(&cnt[b], 1u);
        s_lead = (prev == 31u) ? 1 : 0;
    }
    __syncthreads();
    if (!s_lead) return;

    // ---- leader WG (last arriver): finalize this batch ----
    __threadfence();
    if (tid < 128) lmask[tid] = atomicOr(&gadj[b * 128 + tid], 0u);  // coherent read
    __syncthreads();

    unsigned long long m = 0ull;
    if (tid < 64) {
        m = ((unsigned long long)lmask[tid * 2 + 1] << 32) | lmask[tid * 2];
        for (int j = 0; j < 64; ++j)           // symmetrize: column bits
            if (lmask[j * 2 + (tid >> 5)] & (1u << (tid & 31))) m |= 1ull << j;
        labels[tid] = tid;
    }
    __syncthreads();

    for (int it = 0; it < 64; ++it) {          // synchronous min-label propagation
        int mn = 0;
        if (tid < 64) {
            mn = labels[tid];
            unsigned long long mm = m;
            while (mm) {
                int j = __ffsll(mm) - 1;
                int lj = labels[j];
                mn = mn < lj ? mn : lj;
                mm &= mm - 1;
            }
        }
        __syncthreads();
        if (tid < 64) labels[tid] = mn;
        __syncthreads();
    }

    if (tid < 64) {
        unsigned long long hi_mask = (tid < 63) ? (~0ull << (tid + 1)) : 0ull;
        int myedges = __popcll(m & hi_mask);
        int mycomp  = (labels[tid] == tid) ? 1 : 0;
        #pragma unroll
        for (int off = 32; off >= 1; off >>= 1) {
            myedges += __shfl_down(myedges, off);
            mycomp  += __shfl_down(mycomp, off);
        }
        if (tid == 0) {
            float beta0 = (float)mycomp;
            float beta1 = (float)(myedges - (64 - mycomp));
            out[b]      = beta0;
            out[8 + b]  = beta1;
            out[16 + b] = beta0 / 64.f;
            out[24 + b] = (beta1 > 3.f) ? 1.f : 0.f;
        }
    }
}

// ---------------------------------------------------------------------------
extern "C" void kernel_launch(void* const* d_in, const int* in_sizes, int n_in,
                              void* d_out, int out_size, void* d_ws, size_t ws_size,
                              hipStream_t stream)
{
    const float* emb = (const float*)d_in[0];
    const float* cs  = (const float*)d_in[1];
    float* out = (float*)d_out;

    char* ws = (char*)d_ws;
    unsigned long long* rec   = (unsigned long long*)(ws);
    unsigned long long* bcast = (unsigned long long*)(ws + 8192);
    unsigned int*       gadj  = (unsigned int*)(ws + 73728);
    unsigned int*       cnt   = (unsigned int*)(ws + 77824);

    hipLaunchKernelGGL(init_kernel, dim3(20), dim3(1024), 0, stream,
                       (unsigned int*)ws);
    hipLaunchKernelGGL(fps_all_kernel, dim3(256), dim3(TPB), 0, stream,
                       emb, cs, rec, bcast, gadj, cnt, out);
}